// Round 1
// baseline (181.982 us; speedup 1.0000x reference)
//
#include <hip/hip_runtime.h>

#define INV_SQRT2 0.70710678118654752f
#define SQRT3     1.73205080756887729f
#define INV_SQRT3 0.57735026918962576f
#define INV_SQRT6 0.40824829046386302f
#define PW1_000   0.70710678118654752f   // sqrt(0.5)
#define PW1_112   2.23606797749978970f   // sqrt(5)
#define K_P       0.70710678118654752f   // PW1_011*INV_SQRT3 = PW1_101*INV_SQRT3 = PW1_111*INV_SQRT6
#define K_V0      0.40824829046386302f   // PW1_110*INV_SQRT3
#define PW2       0.15309310892394863f   // sqrt(3/128)
#define NC        0.31622776601683794f   // 1/sqrt(10)
#define NC2       0.18257418583505537f   // 1/sqrt(30)

// D[0]=dot(t1_000,t2_0e) D[1]=dot(t1_110,t2_0e) D[2]=dot(t1_011,t2_1e)
// D[3]=dot(t1_101,t2_1e) D[4]=dot(t1_111,t2_1o) D[5]=dot(t1_112,t2_2e)
__global__ void k_dots(const float* t1_000, const float* t1_011, const float* t1_101,
                       const float* t1_110, const float* t1_111, const float* t1_112,
                       const float* t2_0e, const float* t2_1e, const float* t2_1o,
                       const float* t2_2e, float* D) {
    int l = threadIdx.x;  // 64 threads, one wave
    auto wdot = [&](const float* a, const float* b, int len) -> float {
        float v = (l < len) ? a[l] * b[l] : 0.0f;
        for (int off = 32; off > 0; off >>= 1) v += __shfl_down(v, off);
        return v;
    };
    float d0 = wdot(t1_000, t2_0e, 64);
    float d1 = wdot(t1_110, t2_0e, 64);
    float d2 = wdot(t1_011, t2_1e, 24);
    float d3 = wdot(t1_101, t2_1e, 24);
    float d4 = wdot(t1_111, t2_1o, 24);
    float d5 = wdot(t1_112, t2_2e, 16);
    if (l == 0) { D[0]=d0; D[1]=d1; D[2]=d2; D[3]=d3; D[4]=d4; D[5]=d5; }
}

// h[n][4][4]: channel 0 zeroed (edge scatter fills it), channels 1..3 = [1, sqrt3*emb[nf]]
__global__ void k_fill_h(const int* __restrict__ nf, const float* __restrict__ emb,
                         float* __restrict__ h, int n) {
    int tid = blockIdx.x * blockDim.x + threadIdx.x;
    if (tid >= n * 4) return;
    int v = tid >> 2, c = tid & 3;
    float* hv = h + v * 16 + c * 4;
    if (c == 0) {
        hv[0] = 0.0f; hv[1] = 0.0f; hv[2] = 0.0f; hv[3] = 0.0f;
    } else {
        int idx = nf[v * 3 + (c - 1)];
        hv[0] = 1.0f;
        hv[1] = SQRT3 * emb[idx * 3 + 0];
        hv[2] = SQRT3 * emb[idx * 3 + 1];
        hv[3] = SQRT3 * emb[idx * 3 + 2];
    }
}

// phase 1 edge scatter: h[dst,0,:] += INV_SQRT2 * [1, sqrt3*(r[src]-r[dst])]
__global__ void k_edge1(const float* __restrict__ rv, const int* __restrict__ esrc,
                        const int* __restrict__ edst, float* __restrict__ h, int E, int n) {
    int e = blockIdx.x * blockDim.x + threadIdx.x;
    if (e >= E) return;
    int d = edst[e];
    if (d >= n) return;               // padded edge
    int s = esrc[e];
    float ex = rv[s*3+0] - rv[d*3+0];
    float ey = rv[s*3+1] - rv[d*3+1];
    float ez = rv[s*3+2] - rv[d*3+2];
    atomicAdd(h + d*16 + 0, INV_SQRT2);
    atomicAdd(h + d*16 + 1, INV_SQRT2 * SQRT3 * ex);
    atomicAdd(h + d*16 + 2, INV_SQRT2 * SQRT3 * ey);
    atomicAdd(h + d*16 + 3, INV_SQRT2 * SQRT3 * ez);
}

// phase 2: per (edge,channel); compressed 16-value mid-features scattered to Mid[dst][c][16]
__global__ void k_edge2(const float* __restrict__ rv, const int* __restrict__ esrc,
                        const int* __restrict__ edst, const float* __restrict__ h,
                        float* __restrict__ Mid, int E, int n) {
    int tid = blockIdx.x * blockDim.x + threadIdx.x;
    if (tid >= E * 4) return;
    int e = tid >> 2, c = tid & 3;
    int d = edst[e];
    if (d >= n) return;
    int s = esrc[e];
    float s1x = SQRT3 * (rv[s*3+0] - rv[d*3+0]);
    float s1y = SQRT3 * (rv[s*3+1] - rv[d*3+1]);
    float s1z = SQRT3 * (rv[s*3+2] - rv[d*3+2]);
    const float* hs = h + s*16 + c*4;
    float a0  = hs[0];
    float a1x = hs[1], a1y = hs[2], a1z = hs[3];
    float dotv = a1x*s1x + a1y*s1y + a1z*s1z;
    float crx = a1y*s1z - a1z*s1y;
    float cry = a1z*s1x - a1x*s1z;
    float crz = a1x*s1y - a1y*s1x;
    float v[16];
    v[0]  = PW1_000 * a0;                         // -> m0 * t1_000
    v[1]  = K_V0 * dotv;                          // -> m0 * t1_110
    v[2]  = K_P * a0 * s1x;                       // p011
    v[3]  = K_P * a0 * s1y;
    v[4]  = K_P * a0 * s1z;
    v[5]  = K_P * a1x;                            // p101
    v[6]  = K_P * a1y;
    v[7]  = K_P * a1z;
    v[8]  = K_P * crx;                            // o1e cross
    v[9]  = K_P * cry;
    v[10] = K_P * crz;
    v[11] = PW1_112 * NC  * (a1x*s1y + a1y*s1x);  // t2v via C112
    v[12] = PW1_112 * NC  * (a1y*s1z + a1z*s1y);
    v[13] = PW1_112 * NC2 * (2.0f*a1z*s1z - a1x*s1x - a1y*s1y);
    v[14] = PW1_112 * NC  * (a1x*s1z + a1z*s1x);
    v[15] = PW1_112 * NC  * (a1x*s1x - a1y*s1y);
    float* md = Mid + d*64 + c*16;
    #pragma unroll
    for (int k = 0; k < 16; ++k) atomicAdd(md + k, INV_SQRT2 * v[k]);
}

// phase 3: per edge; reconstruct layer-2 via precomputed weight dots, sum channels, scatter to out
__global__ void k_edge3(const float* __restrict__ rv, const int* __restrict__ esrc,
                        const int* __restrict__ edst, const float* __restrict__ Mid,
                        const float* __restrict__ D, float* __restrict__ out, int E, int n) {
    int e = blockIdx.x * blockDim.x + threadIdx.x;
    if (e >= E) return;
    int d = edst[e];
    if (d >= n) return;
    int s = esrc[e];
    float s1x = SQRT3 * (rv[s*3+0] - rv[d*3+0]);
    float s1y = SQRT3 * (rv[s*3+1] - rv[d*3+1]);
    float s1z = SQRT3 * (rv[s*3+2] - rv[d*3+2]);
    float D00 = D[0], D01 = D[1], D2a = D[2], D2b = D[3], D3 = D[4], D4 = D[5];
    float ox = 0.0f, oy = 0.0f, oz = 0.0f;
    const float* g = Mid + s*64;
    #pragma unroll
    for (int c = 0; c < 4; ++c) {
        const float* G = g + c*16;
        float A0 = G[0], A1 = G[1];
        // q1
        float q = INV_SQRT3 * (A0*D00 + A1*D01);
        ox += q * s1x; oy += q * s1y; oz += q * s1z;
        // q2: INV_SQRT6 * (D2a*(G011 x s1) + D2b*(G101 x s1))
        float c1x = G[3]*s1z - G[4]*s1y;
        float c1y = G[4]*s1x - G[2]*s1z;
        float c1z = G[2]*s1y - G[3]*s1x;
        float c2x = G[6]*s1z - G[7]*s1y;
        float c2y = G[7]*s1x - G[5]*s1z;
        float c2z = G[5]*s1y - G[6]*s1x;
        ox += INV_SQRT6 * (D2a*c1x + D2b*c2x);
        oy += INV_SQRT6 * (D2a*c1y + D2b*c2y);
        oz += INV_SQRT6 * (D2a*c1z + D2b*c2z);
        // q3: INV_SQRT3 * D3 * Gcr
        ox += INV_SQRT3 * D3 * G[8];
        oy += INV_SQRT3 * D3 * G[9];
        oz += INV_SQRT3 * D3 * G[10];
        // q4: D4 * sum_{i,j} G2[i]*s1[j]*C112[j,k,i]
        float g0 = G[11], g1 = G[12], g2 = G[13], g3 = G[14], g4 = G[15];
        float r4x = NC*(s1y*g0 + s1z*g3 + s1x*g4) - NC2*s1x*g2;
        float r4y = NC*(s1x*g0 + s1z*g1 - s1y*g4) - NC2*s1y*g2;
        float r4z = NC*(s1y*g1 + s1x*g3) + 2.0f*NC2*s1z*g2;
        ox += D4 * r4x;
        oy += D4 * r4y;
        oz += D4 * r4z;
    }
    atomicAdd(out + d*3 + 0, PW2 * INV_SQRT2 * ox);
    atomicAdd(out + d*3 + 1, PW2 * INV_SQRT2 * oy);
    atomicAdd(out + d*3 + 2, PW2 * INV_SQRT2 * oz);
}

extern "C" void kernel_launch(void* const* d_in, const int* in_sizes, int n_in,
                              void* d_out, int out_size, void* d_ws, size_t ws_size,
                              hipStream_t stream) {
    const int*   nf     = (const int*)  d_in[0];
    const float* rv     = (const float*)d_in[1];
    const int*   esrc   = (const int*)  d_in[2];
    const int*   edst   = (const int*)  d_in[3];
    const float* emb    = (const float*)d_in[4];
    const float* t1_000 = (const float*)d_in[5];
    const float* t1_011 = (const float*)d_in[6];
    const float* t1_101 = (const float*)d_in[7];
    const float* t1_110 = (const float*)d_in[8];
    const float* t1_111 = (const float*)d_in[9];
    const float* t1_112 = (const float*)d_in[10];
    const float* t2_0e  = (const float*)d_in[11];
    const float* t2_1e  = (const float*)d_in[12];
    const float* t2_1o  = (const float*)d_in[13];
    const float* t2_2e  = (const float*)d_in[14];

    const int n = in_sizes[1] / 3;   // 2048 nodes
    const int E = in_sizes[2];       // 40960 edges

    float* h   = (float*)d_ws;       // n*16 floats
    float* Mid = h + n * 16;         // n*64 floats
    float* Dd  = Mid + n * 64;       // 6 floats
    float* out = (float*)d_out;

    hipMemsetAsync(Mid, 0, (size_t)n * 64 * sizeof(float), stream);
    hipMemsetAsync(out, 0, (size_t)out_size * sizeof(float), stream);

    k_dots<<<1, 64, 0, stream>>>(t1_000, t1_011, t1_101, t1_110, t1_111, t1_112,
                                 t2_0e, t2_1e, t2_1o, t2_2e, Dd);
    k_fill_h<<<(n * 4 + 255) / 256, 256, 0, stream>>>(nf, emb, h, n);
    k_edge1<<<(E + 255) / 256, 256, 0, stream>>>(rv, esrc, edst, h, E, n);
    k_edge2<<<(E * 4 + 255) / 256, 256, 0, stream>>>(rv, esrc, edst, h, Mid, E, n);
    k_edge3<<<(E + 255) / 256, 256, 0, stream>>>(rv, esrc, edst, Mid, Dd, out, E, n);
}

// Round 2
// 115.213 us; speedup vs baseline: 1.5795x; 1.5795x over previous
//
#include <hip/hip_runtime.h>

#define INV_SQRT2 0.70710678118654752f
#define SQRT3     1.73205080756887729f
#define INV_SQRT3 0.57735026918962576f
#define INV_SQRT6 0.40824829046386302f
#define PW1_000   0.70710678118654752f   // sqrt(0.5)
#define PW1_112   2.23606797749978970f   // sqrt(5)
#define K_P       0.70710678118654752f   // PW1_011*INV_SQRT3 = PW1_101*INV_SQRT3 = PW1_111*INV_SQRT6
#define K_V0      0.40824829046386302f   // PW1_110*INV_SQRT3
#define PW2       0.15309310892394863f   // sqrt(3/128)
#define NC        0.31622776601683794f   // 1/sqrt(10)
#define NC2       0.18257418583505537f   // 1/sqrt(30)

// ---- CSR build ---------------------------------------------------------

__global__ void k_deg(const int* __restrict__ edst, int* __restrict__ deg, int E, int n) {
    int e = blockIdx.x * blockDim.x + threadIdx.x;
    if (e >= E) return;
    int d = edst[e];
    if (d < n) atomicAdd(deg + d, 1);
}

// single wave exclusive scan over n degrees -> offs, cur
__global__ void k_scan(const int* __restrict__ deg, int* __restrict__ offs,
                       int* __restrict__ cur, int n) {
    int l = threadIdx.x;               // 64 lanes
    int per = (n + 63) / 64;
    int base = l * per;
    int sum = 0;
    for (int i = 0; i < per; ++i) {
        int idx = base + i;
        if (idx < n) sum += deg[idx];
    }
    int incl = sum;
    for (int off = 1; off < 64; off <<= 1) {
        int t = __shfl_up(incl, off);
        if (l >= off) incl += t;
    }
    int run = incl - sum;              // exclusive
    for (int i = 0; i < per; ++i) {
        int idx = base + i;
        if (idx < n) {
            offs[idx] = run; cur[idx] = run;
            run += deg[idx];
        }
    }
}

// csr[pos] = {s1x, s1y, s1z, bitcast(src)} sorted by dst
__global__ void k_fill(const float* __restrict__ rv, const int* __restrict__ esrc,
                       const int* __restrict__ edst, int* __restrict__ cur,
                       float4* __restrict__ csr, int E, int n) {
    int e = blockIdx.x * blockDim.x + threadIdx.x;
    if (e >= E) return;
    int d = edst[e];
    if (d >= n) return;
    int s = esrc[e];
    float s1x = SQRT3 * (rv[s*3+0] - rv[d*3+0]);
    float s1y = SQRT3 * (rv[s*3+1] - rv[d*3+1]);
    float s1z = SQRT3 * (rv[s*3+2] - rv[d*3+2]);
    int pos = atomicAdd(cur + d, 1);
    csr[pos] = make_float4(s1x, s1y, s1z, __int_as_float(s));
}

// ---- misc: weight dots (block 0) + h channels 1..3 (other blocks) ------

__global__ void k_misc(const float* t1_000, const float* t1_011, const float* t1_101,
                       const float* t1_110, const float* t1_111, const float* t1_112,
                       const float* t2_0e, const float* t2_1e, const float* t2_1o,
                       const float* t2_2e, float* __restrict__ D,
                       const int* __restrict__ nf, const float* __restrict__ emb,
                       float* __restrict__ h, int n) {
    if (blockIdx.x == 0) {
        int l = threadIdx.x;
        if (l >= 64) return;
        auto wdot = [&](const float* a, const float* b, int len) -> float {
            float v = (l < len) ? a[l] * b[l] : 0.0f;
            for (int off = 32; off > 0; off >>= 1) v += __shfl_down(v, off);
            return v;
        };
        float d0 = wdot(t1_000, t2_0e, 64);
        float d1 = wdot(t1_110, t2_0e, 64);
        float d2 = wdot(t1_011, t2_1e, 24);
        float d3 = wdot(t1_101, t2_1e, 24);
        float d4 = wdot(t1_111, t2_1o, 24);
        float d5 = wdot(t1_112, t2_2e, 16);
        if (l == 0) { D[0]=d0; D[1]=d1; D[2]=d2; D[3]=d3; D[4]=d4; D[5]=d5; }
        return;
    }
    int tid = (blockIdx.x - 1) * blockDim.x + threadIdx.x;   // over n*3
    if (tid >= n * 3) return;
    int v = tid / 3, cm = tid - v * 3;                        // c = cm+1
    int idx = nf[tid];
    float4* hv = (float4*)(h + v*16 + (cm + 1)*4);
    *hv = make_float4(1.0f, SQRT3*emb[idx*3+0], SQRT3*emb[idx*3+1], SQRT3*emb[idx*3+2]);
}

// ---- phase 1 gather: h[d,0,:] = INV_SQRT2 * sum_in [1, s1] -------------

__global__ void k_gather1(const float4* __restrict__ csr, const int* __restrict__ offs,
                          const int* __restrict__ deg, float* __restrict__ h, int n) {
    int d = blockIdx.x * blockDim.x + threadIdx.x;
    if (d >= n) return;
    int beg = offs[d], cnt = deg[d];
    float ax = 0.f, ay = 0.f, az = 0.f;
    for (int p = beg; p < beg + cnt; ++p) {
        float4 t = csr[p];
        ax += t.x; ay += t.y; az += t.z;
    }
    float4* hv = (float4*)(h + d*16);
    *hv = make_float4(INV_SQRT2 * (float)cnt, INV_SQRT2*ax, INV_SQRT2*ay, INV_SQRT2*az);
}

// ---- phase 2 gather: Mid[d][c][16] -------------------------------------

__global__ void k_gather2(const float4* __restrict__ csr, const int* __restrict__ offs,
                          const int* __restrict__ deg, const float* __restrict__ h,
                          float* __restrict__ Mid, int n) {
    int tid = blockIdx.x * blockDim.x + threadIdx.x;
    if (tid >= n * 4) return;
    int d = tid >> 2, c = tid & 3;
    int beg = offs[d], cnt = deg[d];
    float A0=0.f, A1=0.f;
    float px=0.f, py=0.f, pz=0.f;       // a0*s1
    float qx=0.f, qy=0.f, qz=0.f;       // a1
    float cx=0.f, cy=0.f, cz=0.f;       // a1 x s1
    float t0=0.f, t1=0.f, t2=0.f, t3=0.f, t4=0.f;  // l=2 harmonics
    for (int p = beg; p < beg + cnt; ++p) {
        float4 t = csr[p];
        int s = __float_as_int(t.w);
        float s1x = t.x, s1y = t.y, s1z = t.z;
        float4 hv = *(const float4*)(h + s*16 + c*4);
        float a0 = hv.x, a1x = hv.y, a1y = hv.z, a1z = hv.w;
        A0 += a0;
        A1 += a1x*s1x + a1y*s1y + a1z*s1z;
        px += a0*s1x; py += a0*s1y; pz += a0*s1z;
        qx += a1x;    qy += a1y;    qz += a1z;
        cx += a1y*s1z - a1z*s1y;
        cy += a1z*s1x - a1x*s1z;
        cz += a1x*s1y - a1y*s1x;
        t0 += a1x*s1y + a1y*s1x;
        t1 += a1y*s1z + a1z*s1y;
        t2 += 2.0f*a1z*s1z - a1x*s1x - a1y*s1y;
        t3 += a1x*s1z + a1z*s1x;
        t4 += a1x*s1x - a1y*s1y;
    }
    const float kA = INV_SQRT2 * PW1_000;
    const float kB = INV_SQRT2 * K_V0;
    const float kP = INV_SQRT2 * K_P;
    const float kT = INV_SQRT2 * PW1_112 * NC;
    const float kU = INV_SQRT2 * PW1_112 * NC2;
    float4* md = (float4*)(Mid + d*64 + c*16);
    md[0] = make_float4(kA*A0, kB*A1, kP*px, kP*py);
    md[1] = make_float4(kP*pz, kP*qx, kP*qy, kP*qz);
    md[2] = make_float4(kP*cx, kP*cy, kP*cz, kT*t0);
    md[3] = make_float4(kT*t1, kU*t2, kT*t3, kT*t4);
}

// ---- phase 3 gather: out[d] --------------------------------------------

__global__ void k_gather3(const float4* __restrict__ csr, const int* __restrict__ offs,
                          const int* __restrict__ deg, const float* __restrict__ Mid,
                          const float* __restrict__ D, float* __restrict__ out, int n) {
    int d = blockIdx.x * blockDim.x + threadIdx.x;
    if (d >= n) return;
    int beg = offs[d], cnt = deg[d];
    float D00 = D[0], D01 = D[1], D2a = D[2], D2b = D[3], D3 = D[4], D4 = D[5];
    float ox = 0.f, oy = 0.f, oz = 0.f;
    for (int p = beg; p < beg + cnt; ++p) {
        float4 t = csr[p];
        int s = __float_as_int(t.w);
        float s1x = t.x, s1y = t.y, s1z = t.z;
        const float4* m4 = (const float4*)(Mid + s*64);
        #pragma unroll
        for (int c = 0; c < 4; ++c) {
            float4 ga = m4[c*4+0], gb = m4[c*4+1], gc = m4[c*4+2], gd = m4[c*4+3];
            float G0=ga.x, G1=ga.y, G2=ga.z, G3=ga.w;
            float G4=gb.x, G5=gb.y, G6=gb.z, G7=gb.w;
            float G8=gc.x, G9=gc.y, G10=gc.z, G11=gc.w;
            float G12=gd.x, G13=gd.y, G14=gd.z, G15=gd.w;
            // q1
            float q = INV_SQRT3 * (G0*D00 + G1*D01);
            ox += q * s1x; oy += q * s1y; oz += q * s1z;
            // q2
            float c1x = G3*s1z - G4*s1y;
            float c1y = G4*s1x - G2*s1z;
            float c1z = G2*s1y - G3*s1x;
            float c2x = G6*s1z - G7*s1y;
            float c2y = G7*s1x - G5*s1z;
            float c2z = G5*s1y - G6*s1x;
            ox += INV_SQRT6 * (D2a*c1x + D2b*c2x);
            oy += INV_SQRT6 * (D2a*c1y + D2b*c2y);
            oz += INV_SQRT6 * (D2a*c1z + D2b*c2z);
            // q3
            ox += INV_SQRT3 * D3 * G8;
            oy += INV_SQRT3 * D3 * G9;
            oz += INV_SQRT3 * D3 * G10;
            // q4
            float r4x = NC*(s1y*G11 + s1z*G14 + s1x*G15) - NC2*s1x*G13;
            float r4y = NC*(s1x*G11 + s1z*G12 - s1y*G15) - NC2*s1y*G13;
            float r4z = NC*(s1y*G12 + s1x*G14) + 2.0f*NC2*s1z*G13;
            ox += D4 * r4x;
            oy += D4 * r4y;
            oz += D4 * r4z;
        }
    }
    out[d*3+0] = PW2 * INV_SQRT2 * ox;
    out[d*3+1] = PW2 * INV_SQRT2 * oy;
    out[d*3+2] = PW2 * INV_SQRT2 * oz;
}

extern "C" void kernel_launch(void* const* d_in, const int* in_sizes, int n_in,
                              void* d_out, int out_size, void* d_ws, size_t ws_size,
                              hipStream_t stream) {
    const int*   nf     = (const int*)  d_in[0];
    const float* rv     = (const float*)d_in[1];
    const int*   esrc   = (const int*)  d_in[2];
    const int*   edst   = (const int*)  d_in[3];
    const float* emb    = (const float*)d_in[4];
    const float* t1_000 = (const float*)d_in[5];
    const float* t1_011 = (const float*)d_in[6];
    const float* t1_101 = (const float*)d_in[7];
    const float* t1_110 = (const float*)d_in[8];
    const float* t1_111 = (const float*)d_in[9];
    const float* t1_112 = (const float*)d_in[10];
    const float* t2_0e  = (const float*)d_in[11];
    const float* t2_1e  = (const float*)d_in[12];
    const float* t2_1o  = (const float*)d_in[13];
    const float* t2_2e  = (const float*)d_in[14];

    const int n = in_sizes[1] / 3;   // 2048 nodes
    const int E = in_sizes[2];       // 40960 edges

    float4* csr = (float4*)d_ws;                 // E float4
    float*  h   = (float*)d_ws + (size_t)E * 4;  // n*16
    float*  Mid = h + (size_t)n * 16;            // n*64
    float*  Dd  = Mid + (size_t)n * 64;          // 8
    int*    deg = (int*)(Dd + 8);                // n
    int*    offs= deg + n;                       // n
    int*    cur = offs + n;                      // n
    float*  out = (float*)d_out;

    hipMemsetAsync(deg, 0, (size_t)n * sizeof(int), stream);
    k_deg <<<(E + 255) / 256, 256, 0, stream>>>(edst, deg, E, n);
    k_scan<<<1, 64, 0, stream>>>(deg, offs, cur, n);
    k_fill<<<(E + 255) / 256, 256, 0, stream>>>(rv, esrc, edst, cur, csr, E, n);
    k_misc<<<1 + (n * 3 + 255) / 256, 256, 0, stream>>>(
        t1_000, t1_011, t1_101, t1_110, t1_111, t1_112,
        t2_0e, t2_1e, t2_1o, t2_2e, Dd, nf, emb, h, n);
    k_gather1<<<(n + 255) / 256, 256, 0, stream>>>(csr, offs, deg, h, n);
    k_gather2<<<(n * 4 + 255) / 256, 256, 0, stream>>>(csr, offs, deg, h, Mid, n);
    k_gather3<<<(n + 255) / 256, 256, 0, stream>>>(csr, offs, deg, Mid, Dd, out, n);
}

// Round 3
// 44.270 us; speedup vs baseline: 4.1108x; 2.6025x over previous
//
#include <hip/hip_runtime.h>

#define INV_SQRT2 0.70710678118654752f
#define SQRT3     1.73205080756887729f
#define INV_SQRT3 0.57735026918962576f
#define INV_SQRT6 0.40824829046386302f
#define PW1_000   0.70710678118654752f   // sqrt(0.5)
#define PW1_112   2.23606797749978970f   // sqrt(5)
#define K_P       0.70710678118654752f   // PW1_011*INV_SQRT3 = PW1_101*INV_SQRT3 = PW1_111*INV_SQRT6
#define K_V0      0.40824829046386302f   // PW1_110*INV_SQRT3
#define PW2       0.15309310892394863f   // sqrt(3/128)
#define NC        0.31622776601683794f   // 1/sqrt(10)
#define NC2       0.18257418583505537f   // 1/sqrt(30)

// ---- prep: deg atomics (blocks [0,degB)), weight dots (block degB),
// ----       h channels 1..3 (blocks > degB) ----------------------------
__global__ void k_prep(const int* __restrict__ edst, int* __restrict__ deg, int E, int n,
                       const float* t1_000, const float* t1_011, const float* t1_101,
                       const float* t1_110, const float* t1_111, const float* t1_112,
                       const float* t2_0e, const float* t2_1e, const float* t2_1o,
                       const float* t2_2e, float* __restrict__ D,
                       const int* __restrict__ nf, const float* __restrict__ emb,
                       float* __restrict__ h, int degB) {
    int b = blockIdx.x;
    if (b < degB) {
        int e = b * 256 + threadIdx.x;
        if (e < E) {
            int d = edst[e];
            if (d < n) atomicAdd(deg + d, 1);
        }
        return;
    }
    if (b == degB) {
        int l = threadIdx.x;
        if (l >= 64) return;
        auto wdot = [&](const float* a, const float* bb, int len) -> float {
            float v = (l < len) ? a[l] * bb[l] : 0.0f;
            for (int off = 32; off > 0; off >>= 1) v += __shfl_down(v, off);
            return v;
        };
        float d0 = wdot(t1_000, t2_0e, 64);
        float d1 = wdot(t1_110, t2_0e, 64);
        float d2 = wdot(t1_011, t2_1e, 24);
        float d3 = wdot(t1_101, t2_1e, 24);
        float d4 = wdot(t1_111, t2_1o, 24);
        float d5 = wdot(t1_112, t2_2e, 16);
        if (l == 0) { D[0]=d0; D[1]=d1; D[2]=d2; D[3]=d3; D[4]=d4; D[5]=d5; }
        return;
    }
    int tid = (b - degB - 1) * 256 + threadIdx.x;   // over n*3
    if (tid >= n * 3) return;
    int v = tid / 3, cm = tid - v * 3;              // channel cm+1
    int idx = nf[tid];
    float4* hv = (float4*)(h + v*16 + (cm + 1)*4);
    *hv = make_float4(1.0f, SQRT3*emb[idx*3+0], SQRT3*emb[idx*3+1], SQRT3*emb[idx*3+2]);
}

// single wave exclusive scan over n degrees -> offs, cur
__global__ void k_scan(const int* __restrict__ deg, int* __restrict__ offs,
                       int* __restrict__ cur, int n) {
    int l = threadIdx.x;               // 64 lanes
    int per = (n + 63) / 64;
    int base = l * per;
    int sum = 0;
    for (int i = 0; i < per; ++i) {
        int idx = base + i;
        if (idx < n) sum += deg[idx];
    }
    int incl = sum;
    for (int off = 1; off < 64; off <<= 1) {
        int t = __shfl_up(incl, off);
        if (l >= off) incl += t;
    }
    int run = incl - sum;              // exclusive
    for (int i = 0; i < per; ++i) {
        int idx = base + i;
        if (idx < n) {
            offs[idx] = run; cur[idx] = run;
            run += deg[idx];
        }
    }
}

// csr[pos] = {s1x, s1y, s1z, bitcast(src)} grouped by dst
__global__ void k_fill(const float* __restrict__ rv, const int* __restrict__ esrc,
                       const int* __restrict__ edst, int* __restrict__ cur,
                       float4* __restrict__ csr, int E, int n) {
    int e = blockIdx.x * blockDim.x + threadIdx.x;
    if (e >= E) return;
    int d = edst[e];
    if (d >= n) return;
    int s = esrc[e];
    float s1x = SQRT3 * (rv[s*3+0] - rv[d*3+0]);
    float s1y = SQRT3 * (rv[s*3+1] - rv[d*3+1]);
    float s1z = SQRT3 * (rv[s*3+2] - rv[d*3+2]);
    int pos = atomicAdd(cur + d, 1);
    csr[pos] = make_float4(s1x, s1y, s1z, __int_as_float(s));
}

// ---- phase 1 gather: h[d,0,:] = INV_SQRT2 * [cnt, sum s1]; 4 lanes/node
__global__ void k_gather1(const float4* __restrict__ csr, const int* __restrict__ offs,
                          const int* __restrict__ deg, float* __restrict__ h, int n) {
    int tid = blockIdx.x * blockDim.x + threadIdx.x;
    if (tid >= n * 4) return;
    int d = tid >> 2, lane = tid & 3;
    int beg = offs[d], cnt = deg[d];
    float ax = 0.f, ay = 0.f, az = 0.f;
    for (int p = beg + lane; p < beg + cnt; p += 4) {
        float4 t = csr[p];
        ax += t.x; ay += t.y; az += t.z;
    }
    ax += __shfl_xor(ax, 1, 4); ax += __shfl_xor(ax, 2, 4);
    ay += __shfl_xor(ay, 1, 4); ay += __shfl_xor(ay, 2, 4);
    az += __shfl_xor(az, 1, 4); az += __shfl_xor(az, 2, 4);
    if (lane == 0) {
        float4* hv = (float4*)(h + d*16);
        *hv = make_float4(INV_SQRT2 * (float)cnt, INV_SQRT2*ax, INV_SQRT2*ay, INV_SQRT2*az);
    }
}

// ---- phase 2 gather, channel-summed: Mid[d][16]; 16 lanes/node ---------
// lane = (c<<2)|sub : channel c in [0,4), edge-split sub in [0,4)
__global__ void k_gather2(const float4* __restrict__ csr, const int* __restrict__ offs,
                          const int* __restrict__ deg, const float* __restrict__ h,
                          float* __restrict__ Mid, int n) {
    int tid = blockIdx.x * blockDim.x + threadIdx.x;
    if (tid >= n * 16) return;
    int d = tid >> 4, lane = tid & 15;
    int c = lane >> 2, sub = lane & 3;
    int beg = offs[d], cnt = deg[d];
    float A0=0.f, A1=0.f;
    float px=0.f, py=0.f, pz=0.f;
    float qx=0.f, qy=0.f, qz=0.f;
    float cx=0.f, cy=0.f, cz=0.f;
    float t0=0.f, t1=0.f, t2=0.f, t3=0.f, t4=0.f;
    for (int p = beg + sub; p < beg + cnt; p += 4) {
        float4 t = csr[p];
        int s = __float_as_int(t.w);
        float s1x = t.x, s1y = t.y, s1z = t.z;
        float4 hv = *(const float4*)(h + s*16 + c*4);
        float a0 = hv.x, a1x = hv.y, a1y = hv.z, a1z = hv.w;
        A0 += a0;
        A1 += a1x*s1x + a1y*s1y + a1z*s1z;
        px += a0*s1x; py += a0*s1y; pz += a0*s1z;
        qx += a1x;    qy += a1y;    qz += a1z;
        cx += a1y*s1z - a1z*s1y;
        cy += a1z*s1x - a1x*s1z;
        cz += a1x*s1y - a1y*s1x;
        t0 += a1x*s1y + a1y*s1x;
        t1 += a1y*s1z + a1z*s1y;
        t2 += 2.0f*a1z*s1z - a1x*s1x - a1y*s1y;
        t3 += a1x*s1z + a1z*s1x;
        t4 += a1x*s1x - a1y*s1y;
    }
#define RED16(v) v += __shfl_xor(v,1,16); v += __shfl_xor(v,2,16); \
                 v += __shfl_xor(v,4,16); v += __shfl_xor(v,8,16);
    RED16(A0) RED16(A1)
    RED16(px) RED16(py) RED16(pz)
    RED16(qx) RED16(qy) RED16(qz)
    RED16(cx) RED16(cy) RED16(cz)
    RED16(t0) RED16(t1) RED16(t2) RED16(t3) RED16(t4)
#undef RED16
    if (lane == 0) {
        const float kA = INV_SQRT2 * PW1_000;
        const float kB = INV_SQRT2 * K_V0;
        const float kP = INV_SQRT2 * K_P;
        const float kT = INV_SQRT2 * PW1_112 * NC;
        const float kU = INV_SQRT2 * PW1_112 * NC2;
        float4* md = (float4*)(Mid + d*16);
        md[0] = make_float4(kA*A0, kB*A1, kP*px, kP*py);
        md[1] = make_float4(kP*pz, kP*qx, kP*qy, kP*qz);
        md[2] = make_float4(kP*cx, kP*cy, kP*cz, kT*t0);
        md[3] = make_float4(kT*t1, kU*t2, kT*t3, kT*t4);
    }
}

// ---- phase 3 gather: out[d]; 16 lanes/node -----------------------------
__global__ void k_gather3(const float4* __restrict__ csr, const int* __restrict__ offs,
                          const int* __restrict__ deg, const float* __restrict__ Mid,
                          const float* __restrict__ D, float* __restrict__ out, int n) {
    int tid = blockIdx.x * blockDim.x + threadIdx.x;
    if (tid >= n * 16) return;
    int d = tid >> 4, lane = tid & 15;
    int beg = offs[d], cnt = deg[d];
    float D00 = D[0], D01 = D[1], D2a = D[2], D2b = D[3], D3 = D[4], D4 = D[5];
    float ox = 0.f, oy = 0.f, oz = 0.f;
    for (int p = beg + lane; p < beg + cnt; p += 16) {
        float4 t = csr[p];
        int s = __float_as_int(t.w);
        float s1x = t.x, s1y = t.y, s1z = t.z;
        const float4* m4 = (const float4*)(Mid + s*16);
        float4 ga = m4[0], gb = m4[1], gc = m4[2], gd = m4[3];
        float G0=ga.x, G1=ga.y, G2=ga.z, G3=ga.w;
        float G4=gb.x, G5=gb.y, G6=gb.z, G7=gb.w;
        float G8=gc.x, G9=gc.y, G10=gc.z, G11=gc.w;
        float G12=gd.x, G13=gd.y, G14=gd.z, G15=gd.w;
        // q1
        float q = INV_SQRT3 * (G0*D00 + G1*D01);
        ox += q * s1x; oy += q * s1y; oz += q * s1z;
        // q2
        float c1x = G3*s1z - G4*s1y;
        float c1y = G4*s1x - G2*s1z;
        float c1z = G2*s1y - G3*s1x;
        float c2x = G6*s1z - G7*s1y;
        float c2y = G7*s1x - G5*s1z;
        float c2z = G5*s1y - G6*s1x;
        ox += INV_SQRT6 * (D2a*c1x + D2b*c2x);
        oy += INV_SQRT6 * (D2a*c1y + D2b*c2y);
        oz += INV_SQRT6 * (D2a*c1z + D2b*c2z);
        // q3
        ox += INV_SQRT3 * D3 * G8;
        oy += INV_SQRT3 * D3 * G9;
        oz += INV_SQRT3 * D3 * G10;
        // q4
        ox += D4 * (NC*(s1y*G11 + s1z*G14 + s1x*G15) - NC2*s1x*G13);
        oy += D4 * (NC*(s1x*G11 + s1z*G12 - s1y*G15) - NC2*s1y*G13);
        oz += D4 * (NC*(s1y*G12 + s1x*G14) + 2.0f*NC2*s1z*G13);
    }
#define RED16(v) v += __shfl_xor(v,1,16); v += __shfl_xor(v,2,16); \
                 v += __shfl_xor(v,4,16); v += __shfl_xor(v,8,16);
    RED16(ox) RED16(oy) RED16(oz)
#undef RED16
    if (lane == 0) {
        out[d*3+0] = PW2 * INV_SQRT2 * ox;
        out[d*3+1] = PW2 * INV_SQRT2 * oy;
        out[d*3+2] = PW2 * INV_SQRT2 * oz;
    }
}

extern "C" void kernel_launch(void* const* d_in, const int* in_sizes, int n_in,
                              void* d_out, int out_size, void* d_ws, size_t ws_size,
                              hipStream_t stream) {
    const int*   nf     = (const int*)  d_in[0];
    const float* rv     = (const float*)d_in[1];
    const int*   esrc   = (const int*)  d_in[2];
    const int*   edst   = (const int*)  d_in[3];
    const float* emb    = (const float*)d_in[4];
    const float* t1_000 = (const float*)d_in[5];
    const float* t1_011 = (const float*)d_in[6];
    const float* t1_101 = (const float*)d_in[7];
    const float* t1_110 = (const float*)d_in[8];
    const float* t1_111 = (const float*)d_in[9];
    const float* t1_112 = (const float*)d_in[10];
    const float* t2_0e  = (const float*)d_in[11];
    const float* t2_1e  = (const float*)d_in[12];
    const float* t2_1o  = (const float*)d_in[13];
    const float* t2_2e  = (const float*)d_in[14];

    const int n = in_sizes[1] / 3;   // 2048 nodes
    const int E = in_sizes[2];       // 40960 edges

    float4* csr = (float4*)d_ws;                 // E float4
    float*  h   = (float*)d_ws + (size_t)E * 4;  // n*16
    float*  Mid = h + (size_t)n * 16;            // n*16 (channel-summed)
    float*  Dd  = Mid + (size_t)n * 16;          // 8
    int*    deg = (int*)(Dd + 8);                // n
    int*    offs= deg + n;                       // n
    int*    cur = offs + n;                      // n
    float*  out = (float*)d_out;

    const int degB = (E + 255) / 256;
    const int hB   = (n * 3 + 255) / 256;

    hipMemsetAsync(deg, 0, (size_t)n * sizeof(int), stream);
    k_prep<<<degB + 1 + hB, 256, 0, stream>>>(
        edst, deg, E, n,
        t1_000, t1_011, t1_101, t1_110, t1_111, t1_112,
        t2_0e, t2_1e, t2_1o, t2_2e, Dd, nf, emb, h, degB);
    k_scan<<<1, 64, 0, stream>>>(deg, offs, cur, n);
    k_fill<<<degB, 256, 0, stream>>>(rv, esrc, edst, cur, csr, E, n);
    k_gather1<<<(n * 4  + 255) / 256, 256, 0, stream>>>(csr, offs, deg, h, n);
    k_gather2<<<(n * 16 + 255) / 256, 256, 0, stream>>>(csr, offs, deg, h, Mid, n);
    k_gather3<<<(n * 16 + 255) / 256, 256, 0, stream>>>(csr, offs, deg, Mid, Dd, out, n);
}